// Round 5
// baseline (2238.246 us; speedup 1.0000x reference)
//
#include <hip/hip_runtime.h>

#define F_ 513
#define M_ 8
#define T_ 2048
#define K_ 2
#define NITER 20
#define REGC 1e-6
#define EPSR 1e-10
#define TOLC 1e-5
#define NG 64
#define TS 4
#define UPB ((F_ + 3) / 4)
#define YRBLK (4*NG)

typedef double2 cd;
__device__ __forceinline__ cd cmk(double r, double i){ cd z; z.x=r; z.y=i; return z; }
__device__ __forceinline__ cd cadd(cd a, cd b){ return cmk(a.x+b.x, a.y+b.y); }
__device__ __forceinline__ cd csub(cd a, cd b){ return cmk(a.x-b.x, a.y-b.y); }
__device__ __forceinline__ cd cmul(cd a, cd b){ return cmk(a.x*b.x - a.y*b.y, a.x*b.y + a.y*b.x); }
__device__ __forceinline__ cd cconj(cd a){ return cmk(a.x, -a.y); }
__device__ __forceinline__ cd cdiv(cd a, cd b){
  double d = b.x*b.x + b.y*b.y;
  return cmk((a.x*b.x + a.y*b.y)/d, (a.y*b.x - a.x*b.y)/d);
}
__device__ __forceinline__ double cabs2(cd a){ return a.x*a.x + a.y*a.y; }
__device__ __forceinline__ cd shflc(cd v, int l){
  cd r; r.x = __shfl(v.x, l, 64); r.y = __shfl(v.y, l, 64); return r;
}
__device__ __forceinline__ cd sel8(const cd x[8], int idx){
  cd r = x[0];
  #pragma unroll
  for (int q=1;q<8;++q) if (idx==q) r = x[q];
  return r;
}

// pack X (M,T,F,2) -> Xc (F,M,T) complex, via LDS tile transpose; float4 writes.
__global__ __launch_bounds__(256) void pack_kernel(const float2* __restrict__ Xin, float2* __restrict__ Xc){
  __shared__ float tr[64][65];
  __shared__ float ti[64][65];
  int f0 = blockIdx.x*64, t0 = blockIdx.y*64, m = blockIdx.z;
  for (int i = threadIdx.x; i < 64*64; i += 256){
    int tl = i >> 6, fl = i & 63;      // lanes -> consecutive f (coalesced read)
    int f = f0 + fl;
    float2 v; v.x = 0.f; v.y = 0.f;
    if (f < F_) v = Xin[((size_t)m*T_ + (t0 + tl))*F_ + f];
    tr[tl][fl] = v.x; ti[tl][fl] = v.y;
  }
  __syncthreads();
  for (int i = threadIdx.x; i < 64*32; i += 256){
    int fl = i >> 5, tl2 = i & 31;     // lanes -> consecutive t-pairs (coalesced float4 write)
    int f = f0 + fl;
    if (f < F_){
      int t = 2*tl2;
      float4 v;
      v.x = tr[t][fl];   v.y = ti[t][fl];
      v.z = tr[t+1][fl]; v.w = ti[t+1][fl];
      *(float4*)&Xc[((size_t)f*8 + m)*T_ + t0 + t] = v;
    }
  }
}

__global__ __launch_bounds__(256) void winit_kernel(float2* __restrict__ W){
  int idx = blockIdx.x*256 + threadIdx.x;
  if (idx >= F_*64) return;
  int l = idx & 63; int i = l>>3, j = l&7;
  float v = (i==j) ? (i < K_ ? 1.f : -1.f) : 0.f;
  float2 o; o.x = v; o.y = 0.f;
  W[idx] = o;
}

// Covariance partials over a 512-t chunk. grid (F_, TS), block 512 (8 waves).
// lane = (m,n) owns one full 8x8 entry; wave w owns t-slice [w*64, w*64+64).
// No wave shuffles; 8-way cross-wave LDS reduce; coalesced 16B stores.
// MODE 0: Cp[f][s][64] ; MODE 1: Vp[k][f][s][64] using packed wts2[t]=(w0,w1).
template<int MODE>
__global__ __launch_bounds__(512, 8) void cov_kernel(const float2* __restrict__ Xc, const float2* __restrict__ wts2,
                                                     cd* __restrict__ outP, const int* __restrict__ flags){
  if (MODE == 1 && *(volatile const int*)flags) return;
  __shared__ float2 xs[8][514];       // padded: row stride 514 -> broadcast-friendly banks
  __shared__ float2 wsm2[512];
  int f = blockIdx.x, s = blockIdx.y;
  int tid = threadIdx.x;
  int w = tid >> 6, lane = tid & 63;
  int m = lane >> 3, n = lane & 7;
  #pragma unroll
  for (int r=0; r<4; ++r){
    int idx = tid + r*512;            // 2048 float4 slots = 8 rows x 256
    int mm = idx >> 8, q = idx & 255;
    float4 v = ((const float4*)(Xc + ((size_t)f*8 + mm)*T_ + s*512))[q];
    *(float4*)&xs[mm][q*2] = v;
  }
  if (MODE == 1) wsm2[tid] = wts2[s*512 + tid];
  __syncthreads();
  const float2* xm = xs[m];
  const float2* xn = xs[n];
  int tbase = w*64;
  float a0r=0.f, a0i=0.f, a1r=0.f, a1i=0.f;
  #pragma unroll 8
  for (int tt=0; tt<64; tt+=2){
    float4 av = *(const float4*)&xm[tbase+tt];
    float4 bv = *(const float4*)&xn[tbase+tt];
    float zr0 = fmaf(av.x, bv.x, av.y*bv.y);
    float zi0 = fmaf(av.y, bv.x, -av.x*bv.y);
    float zr1 = fmaf(av.z, bv.z, av.w*bv.w);
    float zi1 = fmaf(av.w, bv.z, -av.z*bv.w);
    if (MODE == 0){
      a0r += zr0 + zr1; a0i += zi0 + zi1;
    } else {
      float4 wv = *(const float4*)&wsm2[tbase+tt]; // (w0[t],w1[t],w0[t+1],w1[t+1])
      a0r = fmaf(wv.x, zr0, a0r); a0i = fmaf(wv.x, zi0, a0i);
      a1r = fmaf(wv.y, zr0, a1r); a1i = fmaf(wv.y, zi0, a1i);
      a0r = fmaf(wv.z, zr1, a0r); a0i = fmaf(wv.z, zi1, a0i);
      a1r = fmaf(wv.w, zr1, a1r); a1i = fmaf(wv.w, zi1, a1i);
    }
  }
  __syncthreads();
  float* wred = (float*)&xs[0][0];    // reuse xs (dead) : 4 x 512 floats
  wred[0*512 + w*64 + lane] = a0r;
  wred[1*512 + w*64 + lane] = a0i;
  if (MODE == 1){
    wred[2*512 + w*64 + lane] = a1r;
    wred[3*512 + w*64 + lane] = a1i;
  }
  __syncthreads();
  const double inv = 1.0/(double)T_;
  int nk = (MODE == 0) ? 1 : 2;
  if (tid < nk*64){
    int k = tid >> 6, l = tid & 63;
    float rr = 0.f, ii = 0.f;
    #pragma unroll
    for (int ww=0; ww<8; ++ww){
      rr += wred[(k*2+0)*512 + ww*64 + l];
      ii += wred[(k*2+1)*512 + ww*64 + l];
    }
    cd o = cmk((double)rr*inv, (double)ii*inv);
    if (MODE == 0) outP[((size_t)f*TS + s)*64 + l] = o;
    else           outP[(((size_t)k*F_ + f)*TS + s)*64 + l] = o;
  }
}

// partial r2 over f-groups + fused wts reduction via last-block ticket.
// grid (4, NG), block 256; each thread handles 2 t via float4 loads.
__global__ __launch_bounds__(256) void yr_kernel(const float2* __restrict__ Xc, const float2* __restrict__ Wg,
                                                 float* __restrict__ part, float2* __restrict__ wts2,
                                                 int* __restrict__ flags){
  if (*(volatile const int*)flags) return;
  int g = blockIdx.y;
  int t = (blockIdx.x*256 + threadIdx.x)*2;
  float acc00=0.f, acc01=0.f, acc10=0.f, acc11=0.f;  // [k][tpair]
  for (int f = g; f < F_; f += NG){
    const float2* Wf = Wg + (size_t)f*64;
    float2 y00={0,0}, y01={0,0}, y10={0,0}, y11={0,0};
    #pragma unroll
    for (int m=0;m<8;++m){
      float4 xv = *(const float4*)&Xc[((size_t)f*8 + m)*T_ + t];
      float2 w0 = Wf[m];
      float2 w1 = Wf[8+m];
      y00.x = fmaf(w0.x,xv.x,fmaf(-w0.y,xv.y,y00.x)); y00.y = fmaf(w0.x,xv.y,fmaf(w0.y,xv.x,y00.y));
      y10.x = fmaf(w1.x,xv.x,fmaf(-w1.y,xv.y,y10.x)); y10.y = fmaf(w1.x,xv.y,fmaf(w1.y,xv.x,y10.y));
      y01.x = fmaf(w0.x,xv.z,fmaf(-w0.y,xv.w,y01.x)); y01.y = fmaf(w0.x,xv.w,fmaf(w0.y,xv.z,y01.y));
      y11.x = fmaf(w1.x,xv.z,fmaf(-w1.y,xv.w,y11.x)); y11.y = fmaf(w1.x,xv.w,fmaf(w1.y,xv.z,y11.y));
    }
    acc00 += y00.x*y00.x + y00.y*y00.y;
    acc01 += y01.x*y01.x + y01.y*y01.y;
    acc10 += y10.x*y10.x + y10.y*y10.y;
    acc11 += y11.x*y11.x + y11.y*y11.y;
  }
  *(float2*)&part[((size_t)g*2+0)*T_ + t] = make_float2(acc00, acc01);
  *(float2*)&part[((size_t)g*2+1)*T_ + t] = make_float2(acc10, acc11);
  // last-block ticket -> compute wts2 (deterministic fixed-order sums)
  __shared__ int lastF;
  __threadfence();
  if (threadIdx.x == 0){
    int tk = atomicAdd(&flags[2], 1);
    lastF = (tk == YRBLK-1) ? 1 : 0;
  }
  __syncthreads();
  if (!lastF) return;
  __threadfence();
  int tb = threadIdx.x*8;
  float s0[8], s1[8];
  #pragma unroll
  for (int j=0;j<8;++j){ s0[j]=0.f; s1[j]=0.f; }
  for (int gg=0; gg<NG; ++gg){
    float4 p0a = *(const float4*)&part[((size_t)gg*2+0)*T_ + tb];
    float4 p0b = *(const float4*)&part[((size_t)gg*2+0)*T_ + tb + 4];
    float4 p1a = *(const float4*)&part[((size_t)gg*2+1)*T_ + tb];
    float4 p1b = *(const float4*)&part[((size_t)gg*2+1)*T_ + tb + 4];
    s0[0]+=p0a.x; s0[1]+=p0a.y; s0[2]+=p0a.z; s0[3]+=p0a.w;
    s0[4]+=p0b.x; s0[5]+=p0b.y; s0[6]+=p0b.z; s0[7]+=p0b.w;
    s1[0]+=p1a.x; s1[1]+=p1a.y; s1[2]+=p1a.z; s1[3]+=p1a.w;
    s1[4]+=p1b.x; s1[5]+=p1b.y; s1[6]+=p1b.z; s1[7]+=p1b.w;
  }
  if (threadIdx.x == 0) flags[2] = 0;
  #pragma unroll
  for (int j=0;j<8;++j){
    float w0 = 0.5f / sqrtf(fmaxf(s0[j], 1e-10f));
    float w1 = 0.5f / sqrtf(fmaxf(s1[j], 1e-10f));
    wts2[tb+j] = make_float2(w0, w1);
  }
}

// one wave64 per f; reads TS partials of V and C; fused convergence reduction
__global__ __launch_bounds__(256) void update_kernel(const cd* __restrict__ Vp, const cd* __restrict__ Cp,
                                                     float2* __restrict__ Wg,
                                                     double* __restrict__ dsum, double* __restrict__ osum,
                                                     int* __restrict__ flags){
  if (*(volatile const int*)flags) return;
  int lane = threadIdx.x & 63;
  int w = threadIdx.x >> 6;
  int f = blockIdx.x*4 + w;
  int i = lane >> 3, j = lane & 7;
  double ds = 0.0, os = 0.0;
  if (f < F_){
    float2 wf = Wg[(size_t)f*64 + lane];
    cd Wn = cmk(wf.x, wf.y);
    cd Wold = Wn;
    cd x[8];
    #pragma unroll
    for (int k=0; k<K_; ++k){
      cd Vr = cmk(0,0);
      #pragma unroll
      for (int s2=0; s2<TS; ++s2)
        Vr = cadd(Vr, Vp[(((size_t)k*F_ + f)*TS + s2)*64 + lane]);
      if (i == j) Vr.x += REGC;
      cd temp = cmk(0,0);
      #pragma unroll
      for (int q=0;q<8;++q) temp = cadd(temp, cmul(shflc(Wn, i*8+q), shflc(Vr, q*8+j)));
      cd b = cmk(i==k ? 1.0 : 0.0, 0.0);
      for (int p=0; p<8; ++p){
        double pv = (j==p && i>=p) ? cabs2(temp) : -1.0;
        int pidx = i;
        for (int off=32; off; off>>=1){
          double ov = __shfl_xor(pv, off, 64);
          int oi = __shfl_xor(pidx, off, 64);
          if (ov > pv){ pv = ov; pidx = oi; }
        }
        cd tp = shflc(temp, pidx*8 + j);
        cd tq = shflc(temp, p*8 + j);
        cd bp_ = shflc(b, pidx*8 + j);
        cd bq_ = shflc(b, p*8 + j);
        if (i == p){ temp = tp; b = bp_; }
        else if (i == pidx){ temp = tq; b = bq_; }
        cd tip = shflc(temp, i*8 + p);
        cd tpp = shflc(temp, p*8 + p);
        cd tpj = shflc(temp, p*8 + j);
        cd bpr = shflc(b, p*8 + j);
        cd fac = cdiv(tip, tpp);
        if (i > p){ temp = csub(temp, cmul(fac, tpj)); b = csub(b, cmul(fac, bpr)); }
      }
      #pragma unroll
      for (int p=7; p>=0; --p){
        cd s = shflc(b, p*8);
        #pragma unroll
        for (int q=p+1; q<8; ++q){
          cd tpq = shflc(temp, p*8 + q);
          s = csub(s, cmul(tpq, x[q]));
        }
        x[p] = cdiv(s, shflc(temp, p*8 + p));
      }
      cd xi = sel8(x, i), xj = sel8(x, j);
      cd z = cmul(cconj(xi), Vr);
      double dl = z.x*xj.x - z.y*xj.y;
      for (int off=32; off; off>>=1) dl += __shfl_xor(dl, off, 64);
      double denom = sqrt(dl + EPSR);
      if (i == k){ Wn = cmk(xj.x/denom, -xj.y/denom); }
    }
    cd Cc = cmk(0,0);
    #pragma unroll
    for (int s2=0; s2<TS; ++s2)
      Cc = cadd(Cc, Cp[((size_t)f*TS + s2)*64 + lane]);
    cd tmp = cmk(0,0);
    #pragma unroll
    for (int q=0;q<8;++q) tmp = cadd(tmp, cmul(shflc(Wn, i*8+q), shflc(Cc, q*8+j)));
    cd A = shflc(tmp, 0), B = shflc(tmp, 1), C2 = shflc(tmp, 8), D = shflc(tmp, 9);
    cd det = csub(cmul(A,D), cmul(B,C2));
    cd t0 = shflc(tmp, i);
    cd t1 = shflc(tmp, 8 + i);
    cd Z0 = cdiv(csub(cmul(D,t0), cmul(B,t1)), det);
    cd Z1 = cdiv(csub(cmul(A,t1), cmul(C2,t0)), det);
    if (i >= K_ && j < K_){
      cd Z = (j==0) ? Z0 : Z1;
      Wn = cconj(Z);
    }
    ds = cabs2(csub(Wn, Wold));
    os = cabs2(Wold);
    for (int off=32; off; off>>=1){
      ds += __shfl_xor(ds, off, 64);
      os += __shfl_xor(os, off, 64);
    }
    float2 wo; wo.x = (float)Wn.x; wo.y = (float)Wn.y;
    Wg[(size_t)f*64 + lane] = wo;
  }
  __shared__ double sd[4], so[4];
  __shared__ int lastFlag;
  if (lane == 0){ sd[w] = ds; so[w] = os; }
  __syncthreads();
  if (threadIdx.x == 0){
    dsum[blockIdx.x] = sd[0]+sd[1]+sd[2]+sd[3];
    osum[blockIdx.x] = so[0]+so[1]+so[2]+so[3];
  }
  __threadfence();
  if (threadIdx.x == 0){
    int tk = atomicAdd(&flags[1], 1);
    lastFlag = (tk == UPB-1) ? 1 : 0;
  }
  __syncthreads();
  if (lastFlag && threadIdx.x < 64){
    __threadfence();
    double d=0, o=0;
    for (int idx=lane; idx<UPB; idx+=64){
      d += ((volatile double*)dsum)[idx];
      o += ((volatile double*)osum)[idx];
    }
    for (int off=32; off; off>>=1){ d += __shfl_xor(d, off, 64); o += __shfl_xor(o, off, 64); }
    if (lane == 0){
      flags[1] = 0;
      double rel = sqrt(d) / fmax(sqrt(o), 1.1920928955078125e-7);
      if (rel < TOLC) flags[0] = 1;
    }
  }
}

__global__ __launch_bounds__(256) void scale_kernel(const float2* __restrict__ Wg, float2* __restrict__ scale){
  int f = blockIdx.x*256 + threadIdx.x;
  if (f >= F_) return;
  cd w0[8], w1[8];
  #pragma unroll
  for (int m=0;m<8;++m){
    float2 a = Wg[(size_t)f*64 + m];     w0[m] = cmk(a.x, a.y);
    float2 b = Wg[(size_t)f*64 + 8 + m]; w1[m] = cmk(b.x, b.y);
  }
  cd G00 = cmk(0,0), G01 = cmk(0,0), G11 = cmk(0,0);
  #pragma unroll
  for (int m=0;m<8;++m){
    G00 = cadd(G00, cmul(w0[m], cconj(w0[m])));
    G01 = cadd(G01, cmul(w0[m], cconj(w1[m])));
    G11 = cadd(G11, cmul(w1[m], cconj(w1[m])));
  }
  cd G10 = cconj(G01);
  cd det = csub(cmul(G00,G11), cmul(G01,G10));
  cd I00 = cdiv(G11, det), I01 = cdiv(cmk(-G01.x,-G01.y), det);
  cd I10 = cdiv(cmk(-G10.x,-G10.y), det), I11 = cdiv(G00, det);
  cd c0 = cconj(w0[0]), c1 = cconj(w1[0]);
  cd s0 = cadd(cmul(c0, I00), cmul(c1, I10));
  cd s1 = cadd(cmul(c0, I01), cmul(c1, I11));
  float2 o0; o0.x=(float)s0.x; o0.y=(float)s0.y;
  float2 o1; o1.x=(float)s1.x; o1.y=(float)s1.y;
  scale[(size_t)f*2 + 0] = o0;
  scale[(size_t)f*2 + 1] = o1;
}

// out (K,T,F,2) with scale, via LDS transpose. grid (17, 32)
__global__ __launch_bounds__(256) void out_kernel(const float2* __restrict__ Xc, const float2* __restrict__ Wg,
                                                  const float2* __restrict__ scale, float2* __restrict__ out){
  __shared__ float re0[32][65], im0[32][65], re1[32][65], im1[32][65];
  int f0 = blockIdx.x*32, t0 = blockIdx.y*64;
  int lane = threadIdx.x & 63, w = threadIdx.x >> 6;
  for (int fl = w; fl < 32; fl += 4){
    int f = f0 + fl;
    if (f < F_){
      const float2* Wf = Wg + (size_t)f*64;
      int t = t0 + lane;
      float2 y0; y0.x=0; y0.y=0;
      float2 y1; y1.x=0; y1.y=0;
      #pragma unroll
      for (int m=0;m<8;++m){
        float2 xv = Xc[((size_t)f*8 + m)*T_ + t];
        float2 w0 = Wf[m];
        float2 w1 = Wf[8+m];
        y0.x += w0.x*xv.x - w0.y*xv.y; y0.y += w0.x*xv.y + w0.y*xv.x;
        y1.x += w1.x*xv.x - w1.y*xv.y; y1.y += w1.x*xv.y + w1.y*xv.x;
      }
      float2 s0 = scale[(size_t)f*2 + 0];
      float2 s1 = scale[(size_t)f*2 + 1];
      re0[fl][lane] = s0.x*y0.x - s0.y*y0.y; im0[fl][lane] = s0.x*y0.y + s0.y*y0.x;
      re1[fl][lane] = s1.x*y1.x - s1.y*y1.y; im1[fl][lane] = s1.x*y1.y + s1.y*y1.x;
    }
  }
  __syncthreads();
  for (int i = threadIdx.x; i < 32*64; i += 256){
    int tl = i >> 5, fl = i & 31;
    int f = f0 + fl;
    if (f < F_){
      int t = t0 + tl;
      float2 o0; o0.x = re0[fl][tl]; o0.y = im0[fl][tl];
      float2 o1; o1.x = re1[fl][tl]; o1.y = im1[fl][tl];
      out[((size_t)(0*T_ + t))*F_ + f] = o0;
      out[((size_t)(1*T_ + t))*F_ + f] = o1;
    }
  }
}

extern "C" void kernel_launch(void* const* d_in, const int* in_sizes, int n_in,
                              void* d_out, int out_size, void* d_ws, size_t ws_size,
                              hipStream_t stream) {
  const float2* Xin = (const float2*)d_in[0];
  char* ws = (char*)d_ws;
  size_t off = 0;
  auto alloc = [&](size_t bytes) -> void* {
    void* p = ws + off;
    off += (bytes + 255) & ~(size_t)255;
    return p;
  };
  float2* Xc   = (float2*)alloc((size_t)F_*M_*T_*8);
  cd*     Cp   = (cd*)alloc((size_t)F_*TS*64*16);
  cd*     Vp   = (cd*)alloc((size_t)K_*F_*TS*64*16);
  float2* W    = (float2*)alloc((size_t)F_*64*8);
  float*  part = (float*)alloc((size_t)NG*K_*T_*4);
  float2* wts2 = (float2*)alloc((size_t)T_*8);
  double* dsum = (double*)alloc((size_t)UPB*8);
  double* osum = (double*)alloc((size_t)UPB*8);
  float2* sc   = (float2*)alloc((size_t)F_*K_*8);
  int*    flags= (int*)alloc(256);
  if (off > ws_size) return;

  hipMemsetAsync(flags, 0, 12, stream);

  pack_kernel<<<dim3(9, 32, 8), 256, 0, stream>>>(Xin, Xc);
  winit_kernel<<<(F_*64 + 255)/256, 256, 0, stream>>>(W);
  cov_kernel<0><<<dim3(F_, TS), 512, 0, stream>>>(Xc, nullptr, Cp, flags);

  for (int it=0; it<NITER; ++it){
    yr_kernel<<<dim3(4, NG), 256, 0, stream>>>(Xc, W, part, wts2, flags);
    cov_kernel<1><<<dim3(F_, TS), 512, 0, stream>>>(Xc, wts2, Vp, flags);
    update_kernel<<<UPB, 256, 0, stream>>>(Vp, Cp, W, dsum, osum, flags);
  }

  scale_kernel<<<(F_ + 255)/256, 256, 0, stream>>>(W, sc);
  out_kernel<<<dim3(17, 32), 256, 0, stream>>>(Xc, W, sc, (float2*)d_out);
}

// Round 6
// 1670.436 us; speedup vs baseline: 1.3399x; 1.3399x over previous
//
#include <hip/hip_runtime.h>

#define F_ 513
#define M_ 8
#define T_ 2048
#define K_ 2
#define NITER 20
#define REGC 1e-6
#define EPSR 1e-10
#define TOLC 1e-5
#define NG 256
#define TS 4
#define UPB ((F_ + 3) / 4)

typedef double2 cd;
__device__ __forceinline__ cd cmk(double r, double i){ cd z; z.x=r; z.y=i; return z; }
__device__ __forceinline__ cd cadd(cd a, cd b){ return cmk(a.x+b.x, a.y+b.y); }
__device__ __forceinline__ cd csub(cd a, cd b){ return cmk(a.x-b.x, a.y-b.y); }
__device__ __forceinline__ cd cmul(cd a, cd b){ return cmk(a.x*b.x - a.y*b.y, a.x*b.y + a.y*b.x); }
__device__ __forceinline__ cd cconj(cd a){ return cmk(a.x, -a.y); }
__device__ __forceinline__ cd cdiv(cd a, cd b){
  double d = b.x*b.x + b.y*b.y;
  return cmk((a.x*b.x + a.y*b.y)/d, (a.y*b.x - a.x*b.y)/d);
}
__device__ __forceinline__ double cabs2(cd a){ return a.x*a.x + a.y*a.y; }
__device__ __forceinline__ cd shflc(cd v, int l){
  cd r; r.x = __shfl(v.x, l, 64); r.y = __shfl(v.y, l, 64); return r;
}
__device__ __forceinline__ cd sel8(const cd x[8], int idx){
  cd r = x[0];
  #pragma unroll
  for (int q=1;q<8;++q) if (idx==q) r = x[q];
  return r;
}

// pack X (M,T,F,2) -> Xc (F,M,T) complex, via LDS tile transpose; float4 writes.
__global__ __launch_bounds__(256) void pack_kernel(const float2* __restrict__ Xin, float2* __restrict__ Xc){
  __shared__ float tr[64][65];
  __shared__ float ti[64][65];
  int f0 = blockIdx.x*64, t0 = blockIdx.y*64, m = blockIdx.z;
  for (int i = threadIdx.x; i < 64*64; i += 256){
    int tl = i >> 6, fl = i & 63;
    int f = f0 + fl;
    float2 v; v.x = 0.f; v.y = 0.f;
    if (f < F_) v = Xin[((size_t)m*T_ + (t0 + tl))*F_ + f];
    tr[tl][fl] = v.x; ti[tl][fl] = v.y;
  }
  __syncthreads();
  for (int i = threadIdx.x; i < 64*32; i += 256){
    int fl = i >> 5, tl2 = i & 31;
    int f = f0 + fl;
    if (f < F_){
      int t = 2*tl2;
      float4 v;
      v.x = tr[t][fl];   v.y = ti[t][fl];
      v.z = tr[t+1][fl]; v.w = ti[t+1][fl];
      *(float4*)&Xc[((size_t)f*8 + m)*T_ + t0 + t] = v;
    }
  }
}

__global__ __launch_bounds__(256) void winit_kernel(float2* __restrict__ W){
  int idx = blockIdx.x*256 + threadIdx.x;
  if (idx >= F_*64) return;
  int l = idx & 63; int i = l>>3, j = l&7;
  float v = (i==j) ? (i < K_ ? 1.f : -1.f) : 0.f;
  float2 o; o.x = v; o.y = 0.f;
  W[idx] = o;
}

// Covariance partials over a 512-t chunk. grid (F_, TS), block 512 (8 waves).
// lane = (m,n) owns one full 8x8 entry; wave w owns t-slice [w*64, w*64+64).
template<int MODE>
__global__ __launch_bounds__(512, 8) void cov_kernel(const float2* __restrict__ Xc, const float2* __restrict__ wts2,
                                                     cd* __restrict__ outP, const int* __restrict__ flags){
  if (MODE == 1 && *(volatile const int*)flags) return;
  __shared__ float2 xs[8][514];
  __shared__ float2 wsm2[512];
  int f = blockIdx.x, s = blockIdx.y;
  int tid = threadIdx.x;
  int w = tid >> 6, lane = tid & 63;
  int m = lane >> 3, n = lane & 7;
  #pragma unroll
  for (int r=0; r<4; ++r){
    int idx = tid + r*512;
    int mm = idx >> 8, q = idx & 255;
    float4 v = ((const float4*)(Xc + ((size_t)f*8 + mm)*T_ + s*512))[q];
    *(float4*)&xs[mm][q*2] = v;
  }
  if (MODE == 1) wsm2[tid] = wts2[s*512 + tid];
  __syncthreads();
  const float2* xm = xs[m];
  const float2* xn = xs[n];
  int tbase = w*64;
  float a0r=0.f, a0i=0.f, a1r=0.f, a1i=0.f;
  #pragma unroll 8
  for (int tt=0; tt<64; tt+=2){
    float4 av = *(const float4*)&xm[tbase+tt];
    float4 bv = *(const float4*)&xn[tbase+tt];
    float zr0 = fmaf(av.x, bv.x, av.y*bv.y);
    float zi0 = fmaf(av.y, bv.x, -av.x*bv.y);
    float zr1 = fmaf(av.z, bv.z, av.w*bv.w);
    float zi1 = fmaf(av.w, bv.z, -av.z*bv.w);
    if (MODE == 0){
      a0r += zr0 + zr1; a0i += zi0 + zi1;
    } else {
      float4 wv = *(const float4*)&wsm2[tbase+tt];
      a0r = fmaf(wv.x, zr0, a0r); a0i = fmaf(wv.x, zi0, a0i);
      a1r = fmaf(wv.y, zr0, a1r); a1i = fmaf(wv.y, zi0, a1i);
      a0r = fmaf(wv.z, zr1, a0r); a0i = fmaf(wv.z, zi1, a0i);
      a1r = fmaf(wv.w, zr1, a1r); a1i = fmaf(wv.w, zi1, a1i);
    }
  }
  __syncthreads();
  float* wred = (float*)&xs[0][0];
  wred[0*512 + w*64 + lane] = a0r;
  wred[1*512 + w*64 + lane] = a0i;
  if (MODE == 1){
    wred[2*512 + w*64 + lane] = a1r;
    wred[3*512 + w*64 + lane] = a1i;
  }
  __syncthreads();
  const double inv = 1.0/(double)T_;
  int nk = (MODE == 0) ? 1 : 2;
  if (tid < nk*64){
    int k = tid >> 6, l = tid & 63;
    float rr = 0.f, ii = 0.f;
    #pragma unroll
    for (int ww=0; ww<8; ++ww){
      rr += wred[(k*2+0)*512 + ww*64 + l];
      ii += wred[(k*2+1)*512 + ww*64 + l];
    }
    cd o = cmk((double)rr*inv, (double)ii*inv);
    if (MODE == 0) outP[((size_t)f*TS + s)*64 + l] = o;
    else           outP[(((size_t)k*F_ + f)*TS + s)*64 + l] = o;
  }
}

// partial r2 over f-groups: grid (T_/256, NG); part[g][k][t]
__global__ __launch_bounds__(256) void yr_kernel(const float2* __restrict__ Xc, const float2* __restrict__ Wg,
                                                 float* __restrict__ part, const int* __restrict__ flags){
  if (*(volatile const int*)flags) return;
  int g = blockIdx.y;
  int t = blockIdx.x*256 + threadIdx.x;
  float acc0 = 0.f, acc1 = 0.f;
  for (int f = g; f < F_; f += NG){
    const float2* Wf = Wg + (size_t)f*64;
    float2 y0; y0.x=0; y0.y=0;
    float2 y1; y1.x=0; y1.y=0;
    #pragma unroll
    for (int m=0;m<8;++m){
      float2 xv = Xc[((size_t)f*8 + m)*T_ + t];
      float2 w0 = Wf[m];
      float2 w1 = Wf[8+m];
      y0.x = fmaf(w0.x,xv.x,fmaf(-w0.y,xv.y,y0.x)); y0.y = fmaf(w0.x,xv.y,fmaf(w0.y,xv.x,y0.y));
      y1.x = fmaf(w1.x,xv.x,fmaf(-w1.y,xv.y,y1.x)); y1.y = fmaf(w1.x,xv.y,fmaf(w1.y,xv.x,y1.y));
    }
    acc0 += y0.x*y0.x + y0.y*y0.y;
    acc1 += y1.x*y1.x + y1.y*y1.y;
  }
  part[((size_t)g*2+0)*T_ + t] = acc0;
  part[((size_t)g*2+1)*T_ + t] = acc1;
}

// wts2[t] = (w0,w1); grid 16 x 256, fp64 fixed-order sum over NG partials
__global__ __launch_bounds__(256) void rw_kernel(const float* __restrict__ part, float* __restrict__ wts2f,
                                                 const int* __restrict__ flags){
  if (*(volatile const int*)flags) return;
  int v = blockIdx.x*256 + threadIdx.x;
  int k = v >> 11, t = v & (T_-1);
  double s = 0;
  for (int g=0; g<NG; ++g) s += (double)part[((size_t)g*2+k)*T_ + t];
  wts2f[2*t + k] = (float)(0.5 / sqrt(fmax(s, EPSR)));
}

// one wave64 per f; reads TS partials of V and C; fused convergence reduction
__global__ __launch_bounds__(256) void update_kernel(const cd* __restrict__ Vp, const cd* __restrict__ Cp,
                                                     float2* __restrict__ Wg,
                                                     double* __restrict__ dsum, double* __restrict__ osum,
                                                     int* __restrict__ flags){
  if (*(volatile const int*)flags) return;
  int lane = threadIdx.x & 63;
  int w = threadIdx.x >> 6;
  int f = blockIdx.x*4 + w;
  int i = lane >> 3, j = lane & 7;
  double ds = 0.0, os = 0.0;
  if (f < F_){
    float2 wf = Wg[(size_t)f*64 + lane];
    cd Wn = cmk(wf.x, wf.y);
    cd Wold = Wn;
    cd x[8];
    #pragma unroll
    for (int k=0; k<K_; ++k){
      cd Vr = cmk(0,0);
      #pragma unroll
      for (int s2=0; s2<TS; ++s2)
        Vr = cadd(Vr, Vp[(((size_t)k*F_ + f)*TS + s2)*64 + lane]);
      if (i == j) Vr.x += REGC;
      cd temp = cmk(0,0);
      #pragma unroll
      for (int q=0;q<8;++q) temp = cadd(temp, cmul(shflc(Wn, i*8+q), shflc(Vr, q*8+j)));
      cd b = cmk(i==k ? 1.0 : 0.0, 0.0);
      for (int p=0; p<8; ++p){
        double pv = (j==p && i>=p) ? cabs2(temp) : -1.0;
        int pidx = i;
        for (int off=32; off; off>>=1){
          double ov = __shfl_xor(pv, off, 64);
          int oi = __shfl_xor(pidx, off, 64);
          if (ov > pv){ pv = ov; pidx = oi; }
        }
        cd tp = shflc(temp, pidx*8 + j);
        cd tq = shflc(temp, p*8 + j);
        cd bp_ = shflc(b, pidx*8 + j);
        cd bq_ = shflc(b, p*8 + j);
        if (i == p){ temp = tp; b = bp_; }
        else if (i == pidx){ temp = tq; b = bq_; }
        cd tip = shflc(temp, i*8 + p);
        cd tpp = shflc(temp, p*8 + p);
        cd tpj = shflc(temp, p*8 + j);
        cd bpr = shflc(b, p*8 + j);
        cd fac = cdiv(tip, tpp);
        if (i > p){ temp = csub(temp, cmul(fac, tpj)); b = csub(b, cmul(fac, bpr)); }
      }
      #pragma unroll
      for (int p=7; p>=0; --p){
        cd s = shflc(b, p*8);
        #pragma unroll
        for (int q=p+1; q<8; ++q){
          cd tpq = shflc(temp, p*8 + q);
          s = csub(s, cmul(tpq, x[q]));
        }
        x[p] = cdiv(s, shflc(temp, p*8 + p));
      }
      cd xi = sel8(x, i), xj = sel8(x, j);
      cd z = cmul(cconj(xi), Vr);
      double dl = z.x*xj.x - z.y*xj.y;
      for (int off=32; off; off>>=1) dl += __shfl_xor(dl, off, 64);
      double denom = sqrt(dl + EPSR);
      if (i == k){ Wn = cmk(xj.x/denom, -xj.y/denom); }
    }
    cd Cc = cmk(0,0);
    #pragma unroll
    for (int s2=0; s2<TS; ++s2)
      Cc = cadd(Cc, Cp[((size_t)f*TS + s2)*64 + lane]);
    cd tmp = cmk(0,0);
    #pragma unroll
    for (int q=0;q<8;++q) tmp = cadd(tmp, cmul(shflc(Wn, i*8+q), shflc(Cc, q*8+j)));
    cd A = shflc(tmp, 0), B = shflc(tmp, 1), C2 = shflc(tmp, 8), D = shflc(tmp, 9);
    cd det = csub(cmul(A,D), cmul(B,C2));
    cd t0 = shflc(tmp, i);
    cd t1 = shflc(tmp, 8 + i);
    cd Z0 = cdiv(csub(cmul(D,t0), cmul(B,t1)), det);
    cd Z1 = cdiv(csub(cmul(A,t1), cmul(C2,t0)), det);
    if (i >= K_ && j < K_){
      cd Z = (j==0) ? Z0 : Z1;
      Wn = cconj(Z);
    }
    ds = cabs2(csub(Wn, Wold));
    os = cabs2(Wold);
    for (int off=32; off; off>>=1){
      ds += __shfl_xor(ds, off, 64);
      os += __shfl_xor(os, off, 64);
    }
    float2 wo; wo.x = (float)Wn.x; wo.y = (float)Wn.y;
    Wg[(size_t)f*64 + lane] = wo;
  }
  __shared__ double sd[4], so[4];
  __shared__ int lastFlag;
  if (lane == 0){ sd[w] = ds; so[w] = os; }
  __syncthreads();
  if (threadIdx.x == 0){
    dsum[blockIdx.x] = sd[0]+sd[1]+sd[2]+sd[3];
    osum[blockIdx.x] = so[0]+so[1]+so[2]+so[3];
  }
  __threadfence();
  if (threadIdx.x == 0){
    int tk = atomicAdd(&flags[1], 1);
    lastFlag = (tk == UPB-1) ? 1 : 0;
  }
  __syncthreads();
  if (lastFlag && threadIdx.x < 64){
    __threadfence();
    double d=0, o=0;
    for (int idx=lane; idx<UPB; idx+=64){
      d += ((volatile double*)dsum)[idx];
      o += ((volatile double*)osum)[idx];
    }
    for (int off=32; off; off>>=1){ d += __shfl_xor(d, off, 64); o += __shfl_xor(o, off, 64); }
    if (lane == 0){
      flags[1] = 0;
      double rel = sqrt(d) / fmax(sqrt(o), 1.1920928955078125e-7);
      if (rel < TOLC) flags[0] = 1;
    }
  }
}

__global__ __launch_bounds__(256) void scale_kernel(const float2* __restrict__ Wg, float2* __restrict__ scale){
  int f = blockIdx.x*256 + threadIdx.x;
  if (f >= F_) return;
  cd w0[8], w1[8];
  #pragma unroll
  for (int m=0;m<8;++m){
    float2 a = Wg[(size_t)f*64 + m];     w0[m] = cmk(a.x, a.y);
    float2 b = Wg[(size_t)f*64 + 8 + m]; w1[m] = cmk(b.x, b.y);
  }
  cd G00 = cmk(0,0), G01 = cmk(0,0), G11 = cmk(0,0);
  #pragma unroll
  for (int m=0;m<8;++m){
    G00 = cadd(G00, cmul(w0[m], cconj(w0[m])));
    G01 = cadd(G01, cmul(w0[m], cconj(w1[m])));
    G11 = cadd(G11, cmul(w1[m], cconj(w1[m])));
  }
  cd G10 = cconj(G01);
  cd det = csub(cmul(G00,G11), cmul(G01,G10));
  cd I00 = cdiv(G11, det), I01 = cdiv(cmk(-G01.x,-G01.y), det);
  cd I10 = cdiv(cmk(-G10.x,-G10.y), det), I11 = cdiv(G00, det);
  cd c0 = cconj(w0[0]), c1 = cconj(w1[0]);
  cd s0 = cadd(cmul(c0, I00), cmul(c1, I10));
  cd s1 = cadd(cmul(c0, I01), cmul(c1, I11));
  float2 o0; o0.x=(float)s0.x; o0.y=(float)s0.y;
  float2 o1; o1.x=(float)s1.x; o1.y=(float)s1.y;
  scale[(size_t)f*2 + 0] = o0;
  scale[(size_t)f*2 + 1] = o1;
}

// out (K,T,F,2) with scale, via LDS transpose. grid (17, 32)
__global__ __launch_bounds__(256) void out_kernel(const float2* __restrict__ Xc, const float2* __restrict__ Wg,
                                                  const float2* __restrict__ scale, float2* __restrict__ out){
  __shared__ float re0[32][65], im0[32][65], re1[32][65], im1[32][65];
  int f0 = blockIdx.x*32, t0 = blockIdx.y*64;
  int lane = threadIdx.x & 63, w = threadIdx.x >> 6;
  for (int fl = w; fl < 32; fl += 4){
    int f = f0 + fl;
    if (f < F_){
      const float2* Wf = Wg + (size_t)f*64;
      int t = t0 + lane;
      float2 y0; y0.x=0; y0.y=0;
      float2 y1; y1.x=0; y1.y=0;
      #pragma unroll
      for (int m=0;m<8;++m){
        float2 xv = Xc[((size_t)f*8 + m)*T_ + t];
        float2 w0 = Wf[m];
        float2 w1 = Wf[8+m];
        y0.x += w0.x*xv.x - w0.y*xv.y; y0.y += w0.x*xv.y + w0.y*xv.x;
        y1.x += w1.x*xv.x - w1.y*xv.y; y1.y += w1.x*xv.y + w1.y*xv.x;
      }
      float2 s0 = scale[(size_t)f*2 + 0];
      float2 s1 = scale[(size_t)f*2 + 1];
      re0[fl][lane] = s0.x*y0.x - s0.y*y0.y; im0[fl][lane] = s0.x*y0.y + s0.y*y0.x;
      re1[fl][lane] = s1.x*y1.x - s1.y*y1.y; im1[fl][lane] = s1.x*y1.y + s1.y*y1.x;
    }
  }
  __syncthreads();
  for (int i = threadIdx.x; i < 32*64; i += 256){
    int tl = i >> 5, fl = i & 31;
    int f = f0 + fl;
    if (f < F_){
      int t = t0 + tl;
      float2 o0; o0.x = re0[fl][tl]; o0.y = im0[fl][tl];
      float2 o1; o1.x = re1[fl][tl]; o1.y = im1[fl][tl];
      out[((size_t)(0*T_ + t))*F_ + f] = o0;
      out[((size_t)(1*T_ + t))*F_ + f] = o1;
    }
  }
}

extern "C" void kernel_launch(void* const* d_in, const int* in_sizes, int n_in,
                              void* d_out, int out_size, void* d_ws, size_t ws_size,
                              hipStream_t stream) {
  const float2* Xin = (const float2*)d_in[0];
  char* ws = (char*)d_ws;
  size_t off = 0;
  auto alloc = [&](size_t bytes) -> void* {
    void* p = ws + off;
    off += (bytes + 255) & ~(size_t)255;
    return p;
  };
  float2* Xc   = (float2*)alloc((size_t)F_*M_*T_*8);
  cd*     Cp   = (cd*)alloc((size_t)F_*TS*64*16);
  cd*     Vp   = (cd*)alloc((size_t)K_*F_*TS*64*16);
  float2* W    = (float2*)alloc((size_t)F_*64*8);
  float*  part = (float*)alloc((size_t)NG*K_*T_*4);
  float2* wts2 = (float2*)alloc((size_t)T_*8);
  double* dsum = (double*)alloc((size_t)UPB*8);
  double* osum = (double*)alloc((size_t)UPB*8);
  float2* sc   = (float2*)alloc((size_t)F_*K_*8);
  int*    flags= (int*)alloc(256);
  if (off > ws_size) return;

  hipMemsetAsync(flags, 0, 12, stream);

  pack_kernel<<<dim3(9, 32, 8), 256, 0, stream>>>(Xin, Xc);
  winit_kernel<<<(F_*64 + 255)/256, 256, 0, stream>>>(W);
  cov_kernel<0><<<dim3(F_, TS), 512, 0, stream>>>(Xc, nullptr, Cp, flags);

  for (int it=0; it<NITER; ++it){
    yr_kernel<<<dim3(T_/256, NG), 256, 0, stream>>>(Xc, W, part, flags);
    rw_kernel<<<(K_*T_ + 255)/256, 256, 0, stream>>>(part, (float*)wts2, flags);
    cov_kernel<1><<<dim3(F_, TS), 512, 0, stream>>>(Xc, wts2, Vp, flags);
    update_kernel<<<UPB, 256, 0, stream>>>(Vp, Cp, W, dsum, osum, flags);
  }

  scale_kernel<<<(F_ + 255)/256, 256, 0, stream>>>(W, sc);
  out_kernel<<<dim3(17, 32), 256, 0, stream>>>(Xc, W, sc, (float2*)d_out);
}